// Round 1
// baseline (581.147 us; speedup 1.0000x reference)
//
#include <hip/hip_runtime.h>
#include <math.h>

// Problem constants
#define NB   128        // batch
#define CIN  2048
#define PP   256        // W*H = 16*16
#define KK   16         // top-k nodes
#define CO   256        // conv out channels
#define DO   512        // fc out
#define KC   4096       // K*CO

// ws layout (float offsets)
#define WS_PARTIAL 0                         // [128][32][256] = 1,048,576 floats
#define WS_POS     1048576                   // 2048 ints (stored in float slots)
#define WS_LNORM   1050624                   // 128*256 = 32768 floats
#define WS_NODEST  1083392                   // [2048 c][2048 m] = 4,194,304 floats
#define WS_X       5277696                   // [2048 m][256 o] = 524,288 floats
#define WS_Y       5801984                   // [128][4096] = 524,288 floats

// ---------------------------------------------------------------------------
// K1: partial channel-sum. grid (128, 8), block 256.
// block (n, chunk): 256 c's. thread t: sub=t>>6 (c sub-block of 64), p4=t&63
// (4 positions via float4). Fully coalesced 1KB/wave loads.
__global__ __launch_bounds__(256) void k_reduce(const float* __restrict__ snd,
                                                float* __restrict__ partial) {
    int n = blockIdx.x, chunk = blockIdx.y, t = threadIdx.x;
    int sub = t >> 6, p4 = t & 63;
    const float4* base = (const float4*)(snd + (size_t)n * CIN * PP
                                         + (size_t)(chunk * 256 + sub * 64) * PP) + p4;
    float4 acc = make_float4(0.f, 0.f, 0.f, 0.f);
#pragma unroll 4
    for (int c = 0; c < 64; ++c) {
        float4 v = base[c * 64];
        acc.x += v.x; acc.y += v.y; acc.z += v.z; acc.w += v.w;
    }
    ((float4*)(partial + (size_t)(n * 32 + chunk * 4 + sub) * 256))[p4] = acc;
}

// ---------------------------------------------------------------------------
// K2: per-n: finish reduction, top-16 (desc value, tie -> lower index),
// rows/cols remap, lnorm. grid 128, block 256.
__global__ __launch_bounds__(256) void k_topk_lnorm(const float* __restrict__ partial,
                                                    int* __restrict__ pos,
                                                    float* __restrict__ lnorm) {
    int n = blockIdx.x, t = threadIdx.x;
    __shared__ float val[256];
    __shared__ float sval[256];
    __shared__ int   sidx[256];
    __shared__ int   sel[16];
    __shared__ float rr[16], cc[16], dinv[16];
    __shared__ float Ash[256];

    float s = 0.f;
#pragma unroll 8
    for (int j = 0; j < 32; ++j) s += partial[(size_t)(n * 32 + j) * 256 + t];
    val[t] = s;
    __syncthreads();

    for (int k = 0; k < 16; ++k) {
        sval[t] = val[t]; sidx[t] = t;
        __syncthreads();
        for (int srd = 128; srd > 0; srd >>= 1) {
            if (t < srd) {
                float v1 = sval[t], v2 = sval[t + srd];
                int i1 = sidx[t], i2 = sidx[t + srd];
                if (v2 > v1 || (v2 == v1 && i2 < i1)) { sval[t] = v2; sidx[t] = i2; }
            }
            __syncthreads();
        }
        if (t == 0) { int w = sidx[0]; sel[k] = w; val[w] = -INFINITY; }
        __syncthreads();
    }

    if (t < 16) {
        int idx = sel[t];
        int r = (idx < 16) ? (idx >> 4) : ((idx >> 4) - 1);
        int c = ((idx & 15) == 0) ? 15 : ((idx & 15) - 1);
        pos[n * 16 + t] = r * 16 + c;
        rr[t] = (float)r; cc[t] = (float)c;
    }
    __syncthreads();
    {
        int i = t >> 4, j = t & 15;
        float dr = rr[i] - rr[j], dc = cc[i] - cc[j];
        Ash[t] = expf(-(dr * dr + dc * dc) * (1.0f / 32.0f));
    }
    __syncthreads();
    if (t < 16) {
        float srow = 0.f;
#pragma unroll
        for (int j = 0; j < 16; ++j) srow += Ash[t * 16 + j];
        dinv[t] = rsqrtf(srow);
    }
    __syncthreads();
    {
        int i = t >> 4, j = t & 15;
        lnorm[(size_t)n * 256 + t] = Ash[t] * dinv[i] * dinv[j];
    }
}

// ---------------------------------------------------------------------------
// K3: gather nodes into transposed layout nodesT[c][m], m = n*16+k.
// grid (128 n, 128 c-blocks of 16), block 256. Coalesced full-row reads via
// LDS (rows are L3-resident after K1), selected writes.
__global__ __launch_bounds__(256) void k_gather(const float* __restrict__ snd,
                                                const int* __restrict__ pos,
                                                float* __restrict__ nodesT) {
    int n = blockIdx.x, cb = blockIdx.y, t = threadIdx.x;
    __shared__ float rows[16][256];
    __shared__ int lpos[16];
    if (t < 16) lpos[t] = pos[n * 16 + t];
    const float* src = snd + (size_t)n * CIN * PP + (size_t)cb * 16 * PP;
#pragma unroll
    for (int i = 0; i < 16; ++i) rows[i][t] = src[i * PP + t];
    __syncthreads();
    int cl = t >> 4, k = t & 15;
    nodesT[(size_t)(cb * 16 + cl) * 2048 + n * 16 + k] = rows[cl][lpos[k]];
}

// ---------------------------------------------------------------------------
// K4: conv GEMM + bias + relu. X[m][o] = relu(sum_c nodesT[c][m]*W[o][c] + b[o])
// M=2048, N=256, K=2048. Tiles: 64(m) x 32(o), BK=16, 256 threads, micro 4x2.
// grid (32, 8) = 256 blocks.
__global__ __launch_bounds__(256) void k_conv(const float* __restrict__ At,
                                              const float* __restrict__ W,
                                              const float* __restrict__ bias,
                                              float* __restrict__ X) {
    int bm = blockIdx.x, bo = blockIdx.y, t = threadIdx.x;
    int to = t & 15, tm = t >> 4;
    __shared__ float As[16][64];
    __shared__ float Bs[16 * 34];
    float acc[4][2] = {};
    int m0 = bm * 64, o0 = bo * 32;
    for (int c0 = 0; c0 < 2048; c0 += 16) {
#pragma unroll
        for (int i = 0; i < 4; ++i) {
            int e = i * 256 + t;
            int k = e >> 6, m = e & 63;
            As[k][m] = At[(size_t)(c0 + k) * 2048 + m0 + m];
        }
#pragma unroll
        for (int i = 0; i < 2; ++i) {
            int e = i * 256 + t;
            int o = e >> 4, k = e & 15;
            Bs[k * 34 + o] = W[(size_t)(o0 + o) * 2048 + c0 + k];
        }
        __syncthreads();
#pragma unroll
        for (int k = 0; k < 16; ++k) {
            float4 a = *(const float4*)&As[k][tm * 4];
            float2 b = *(const float2*)&Bs[k * 34 + to * 2];
            acc[0][0] += a.x * b.x; acc[0][1] += a.x * b.y;
            acc[1][0] += a.y * b.x; acc[1][1] += a.y * b.y;
            acc[2][0] += a.z * b.x; acc[2][1] += a.z * b.y;
            acc[3][0] += a.w * b.x; acc[3][1] += a.w * b.y;
        }
        __syncthreads();
    }
#pragma unroll
    for (int i = 0; i < 4; ++i) {
        int m = m0 + tm * 4 + i;
#pragma unroll
        for (int j = 0; j < 2; ++j) {
            int o = o0 + to * 2 + j;
            X[(size_t)m * 256 + o] = fmaxf(acc[i][j] + bias[o], 0.0f);
        }
    }
}

// ---------------------------------------------------------------------------
// K5a: y[n][i][o] = sum_j lnorm[n][i][j] * x[n][j][o]. grid 128, block 256.
__global__ __launch_bounds__(256) void k_lnorm_apply(const float* __restrict__ lnorm,
                                                     const float* __restrict__ X,
                                                     float* __restrict__ Y) {
    int n = blockIdx.x, o = threadIdx.x;
    __shared__ float ln[256];
    ln[o] = lnorm[(size_t)n * 256 + o];
    __syncthreads();
    float xv[16];
#pragma unroll
    for (int j = 0; j < 16; ++j) xv[j] = X[(size_t)(n * 16 + j) * 256 + o];
#pragma unroll
    for (int i = 0; i < 16; ++i) {
        float a = 0.f;
#pragma unroll
        for (int j = 0; j < 16; ++j) a += ln[i * 16 + j] * xv[j];
        Y[(size_t)n * 4096 + i * 256 + o] = a;
    }
}

// ---------------------------------------------------------------------------
// K5b: fc GEMM split-K with atomic accumulate. out[n][d] += sum_k Y[n][k]*Fw[d][k]
// M=128, N=512, K=4096, split into 8 K-chunks of 512.
// Tiles: 32(n) x 64(d), BK=16, 256 threads, micro 2x4. grid (4, 8, 8).
__global__ __launch_bounds__(256) void k_fc(const float* __restrict__ Y,
                                            const float* __restrict__ Fw,
                                            float* __restrict__ out) {
    int bn = blockIdx.x, bd = blockIdx.y, bk = blockIdx.z, t = threadIdx.x;
    int to = t & 15, tm = t >> 4;
    __shared__ float Ys[16 * 34];
    __shared__ float Fs[16 * 68];
    float acc[2][4] = {};
    int n0 = bn * 32, d0 = bd * 64, kbase = bk * 512;
    for (int c0 = kbase; c0 < kbase + 512; c0 += 16) {
#pragma unroll
        for (int i = 0; i < 2; ++i) {
            int e = i * 256 + t;
            int m = e >> 4, k = e & 15;
            Ys[k * 34 + m] = Y[(size_t)(n0 + m) * 4096 + c0 + k];
        }
#pragma unroll
        for (int i = 0; i < 4; ++i) {
            int e = i * 256 + t;
            int d = e >> 4, k = e & 15;
            Fs[k * 68 + d] = Fw[(size_t)(d0 + d) * 4096 + c0 + k];
        }
        __syncthreads();
#pragma unroll
        for (int k = 0; k < 16; ++k) {
            float2 a = *(const float2*)&Ys[k * 34 + tm * 2];
            float4 b = *(const float4*)&Fs[k * 68 + to * 4];
            acc[0][0] += a.x * b.x; acc[0][1] += a.x * b.y;
            acc[0][2] += a.x * b.z; acc[0][3] += a.x * b.w;
            acc[1][0] += a.y * b.x; acc[1][1] += a.y * b.y;
            acc[1][2] += a.y * b.z; acc[1][3] += a.y * b.w;
        }
        __syncthreads();
    }
#pragma unroll
    for (int i = 0; i < 2; ++i) {
        int n = n0 + tm * 2 + i;
#pragma unroll
        for (int j = 0; j < 4; ++j) {
            int d = d0 + to * 4 + j;
            atomicAdd(&out[(size_t)n * 512 + d], acc[i][j]);
        }
    }
}

// ---------------------------------------------------------------------------
// K5c: add fc bias (runs after all k_fc atomics on same stream).
__global__ __launch_bounds__(256) void k_bias(float* __restrict__ out,
                                              const float* __restrict__ fcb) {
    int i = blockIdx.x * 256 + threadIdx.x;
    out[i] += fcb[i & 511];
}

// ---------------------------------------------------------------------------
extern "C" void kernel_launch(void* const* d_in, const int* in_sizes, int n_in,
                              void* d_out, int out_size, void* d_ws, size_t ws_size,
                              hipStream_t stream) {
    const float* snd    = (const float*)d_in[0];
    const float* conv_w = (const float*)d_in[1];
    const float* conv_b = (const float*)d_in[2];
    const float* fc_w   = (const float*)d_in[3];
    const float* fc_b   = (const float*)d_in[4];
    float* out = (float*)d_out;
    float* ws  = (float*)d_ws;

    float* partial = ws + WS_PARTIAL;
    int*   pos     = (int*)(ws + WS_POS);
    float* lnorm   = ws + WS_LNORM;
    float* nodesT  = ws + WS_NODEST;
    float* X       = ws + WS_X;
    float* Y       = ws + WS_Y;

    hipMemsetAsync(d_out, 0, (size_t)NB * DO * sizeof(float), stream);

    k_reduce<<<dim3(128, 8), 256, 0, stream>>>(snd, partial);
    k_topk_lnorm<<<128, 256, 0, stream>>>(partial, pos, lnorm);
    k_gather<<<dim3(128, 128), 256, 0, stream>>>(snd, pos, nodesT);
    k_conv<<<dim3(32, 8), 256, 0, stream>>>(nodesT, conv_w, conv_b, X);
    k_lnorm_apply<<<128, 256, 0, stream>>>(lnorm, X, Y);
    k_fc<<<dim3(4, 8, 8), 256, 0, stream>>>(Y, fc_w, out);
    k_bias<<<256, 256, 0, stream>>>(out, fc_b);
}

// Round 2
// 579.973 us; speedup vs baseline: 1.0020x; 1.0020x over previous
//
#include <hip/hip_runtime.h>
#include <math.h>

// Problem constants
#define NB   128        // batch
#define CIN  2048
#define PP   256        // W*H = 16*16
#define KK   16         // top-k nodes
#define CO   256        // conv out channels
#define DO   512        // fc out

// ws layout (float offsets)
#define WS_PARTIAL 0                         // [128][32][256] = 1,048,576 floats
#define WS_POS     1048576                   // 2048 ints
#define WS_LNORM   1050624                   // 128*256 = 32768 floats
#define WS_NODEST  1083392                   // [2048 c][2048 m] = 4,194,304 floats
#define WS_Y       5277696                   // [128][4096] = 524,288 floats

// ---------------------------------------------------------------------------
// K0: init out with fc bias (replaces memset + separate bias pass).
__global__ __launch_bounds__(256) void k_init(float* __restrict__ out,
                                              const float* __restrict__ fcb) {
    int i = blockIdx.x * 256 + threadIdx.x;
    out[i] = fcb[i & 511];
}

// ---------------------------------------------------------------------------
// K1: partial channel-sum. grid (128, 8), block 256.
__global__ __launch_bounds__(256) void k_reduce(const float* __restrict__ snd,
                                                float* __restrict__ partial) {
    int n = blockIdx.x, chunk = blockIdx.y, t = threadIdx.x;
    int sub = t >> 6, p4 = t & 63;
    const float4* base = (const float4*)(snd + (size_t)n * CIN * PP
                                         + (size_t)(chunk * 256 + sub * 64) * PP) + p4;
    float4 acc = make_float4(0.f, 0.f, 0.f, 0.f);
#pragma unroll 4
    for (int c = 0; c < 64; ++c) {
        float4 v = base[c * 64];
        acc.x += v.x; acc.y += v.y; acc.z += v.z; acc.w += v.w;
    }
    ((float4*)(partial + (size_t)(n * 32 + chunk * 4 + sub) * 256))[p4] = acc;
}

// ---------------------------------------------------------------------------
// K2: finish reduction, top-16 via 64-lane shuffle butterfly + 4-wave LDS
// combine (2 barriers/round vs 8), remap, lnorm. grid 128, block 256.
__global__ __launch_bounds__(256) void k_topk_lnorm(const float* __restrict__ partial,
                                                    int* __restrict__ pos,
                                                    float* __restrict__ lnorm) {
    int n = blockIdx.x, t = threadIdx.x;
    int lane = t & 63, wv = t >> 6;
    __shared__ float wval[4];
    __shared__ int   widx[4];
    __shared__ int   sel[16];
    __shared__ float rr[16], cc[16], dinv[16];
    __shared__ float Ash[256];

    float v = 0.f;
#pragma unroll 8
    for (int j = 0; j < 32; ++j) v += partial[(size_t)(n * 32 + j) * 256 + t];

    for (int k = 0; k < 16; ++k) {
        float bv = v; int bi = t;
#pragma unroll
        for (int off = 32; off > 0; off >>= 1) {
            float ov = __shfl_xor(bv, off, 64);
            int   oi = __shfl_xor(bi, off, 64);
            if (ov > bv || (ov == bv && oi < bi)) { bv = ov; bi = oi; }
        }
        if (lane == 0) { wval[wv] = bv; widx[wv] = bi; }
        __syncthreads();
        float best = wval[0]; int besti = widx[0];
#pragma unroll
        for (int w = 1; w < 4; ++w) {
            float ww = wval[w]; int wi = widx[w];
            if (ww > best || (ww == best && wi < besti)) { best = ww; besti = wi; }
        }
        if (t == besti) v = -INFINITY;
        if (t == 0) sel[k] = besti;
        __syncthreads();
    }

    if (t < 16) {
        int idx = sel[t];
        int r = (idx < 16) ? (idx >> 4) : ((idx >> 4) - 1);
        int c = ((idx & 15) == 0) ? 15 : ((idx & 15) - 1);
        pos[n * 16 + t] = r * 16 + c;
        rr[t] = (float)r; cc[t] = (float)c;
    }
    __syncthreads();
    {
        int i = t >> 4, j = t & 15;
        float dr = rr[i] - rr[j], dc = cc[i] - cc[j];
        Ash[t] = expf(-(dr * dr + dc * dc) * (1.0f / 32.0f));
    }
    __syncthreads();
    if (t < 16) {
        float srow = 0.f;
#pragma unroll
        for (int j = 0; j < 16; ++j) srow += Ash[t * 16 + j];
        dinv[t] = rsqrtf(srow);
    }
    __syncthreads();
    {
        int i = t >> 4, j = t & 15;
        lnorm[(size_t)n * 256 + t] = Ash[t] * dinv[i] * dinv[j];
    }
}

// ---------------------------------------------------------------------------
// K3: gather nodes into nodesT[c][m], m = n*16+k. grid (128, 128), block 256.
// Coalesced full-row reads staged via LDS (rows L3-resident after K1).
__global__ __launch_bounds__(256) void k_gather(const float* __restrict__ snd,
                                                const int* __restrict__ pos,
                                                float* __restrict__ nodesT) {
    int n = blockIdx.x, cb = blockIdx.y, t = threadIdx.x;
    __shared__ float rows[16][256];
    __shared__ int lpos[16];
    if (t < 16) lpos[t] = pos[n * 16 + t];
    const float* src = snd + (size_t)n * CIN * PP + (size_t)cb * 16 * PP;
#pragma unroll
    for (int i = 0; i < 16; ++i) rows[i][t] = src[i * PP + t];
    __syncthreads();
    int cl = t >> 4, k = t & 15;
    nodesT[(size_t)(cb * 16 + cl) * 2048 + n * 16 + k] = rows[cl][lpos[k]];
}

// ---------------------------------------------------------------------------
// K4: conv GEMM + bias + relu + FUSED lnorm apply.
// X[m][o] = relu(sum_c nodesT[c][m]*W[o][c] + b[o]), m = n*16+k.
// A 64m tile = 4 complete graphs (n's), so Y[n,i,o] = sum_j ln[n,i,j]*X[n,j,o]
// is block-local. Tiles 64(m) x 32(o), BK=16, 256 threads, micro 4x2.
// grid (32, 8) = 256 blocks.
__global__ __launch_bounds__(256) void k_conv(const float* __restrict__ At,
                                              const float* __restrict__ W,
                                              const float* __restrict__ bias,
                                              const float* __restrict__ lnorm,
                                              float* __restrict__ Y) {
    int bm = blockIdx.x, bo = blockIdx.y, t = threadIdx.x;
    int to = t & 15, tm = t >> 4;
    __shared__ float As[16][64];
    __shared__ float Bs[16 * 34];
    __shared__ float Xs[64][34];
    __shared__ float lns[4 * 272];   // [nl][i][j] strided i*17+j (bank-conflict-free)
    float acc[4][2] = {};
    int m0 = bm * 64, o0 = bo * 32;

    // stage lnorm rows for this block's 4 n's (1024 floats)
    {
        float4 lv = ((const float4*)(lnorm + (size_t)bm * 1024))[t];
        int e = t * 4;
#pragma unroll
        for (int q = 0; q < 4; ++q) {
            int ee = e + q;
            int nl = ee >> 8, rem = ee & 255, i = rem >> 4, j = rem & 15;
            lns[nl * 272 + i * 17 + j] = (q == 0) ? lv.x : (q == 1) ? lv.y : (q == 2) ? lv.z : lv.w;
        }
    }

    for (int c0 = 0; c0 < 2048; c0 += 16) {
#pragma unroll
        for (int i = 0; i < 4; ++i) {
            int e = i * 256 + t;
            int k = e >> 6, m = e & 63;
            As[k][m] = At[(size_t)(c0 + k) * 2048 + m0 + m];
        }
#pragma unroll
        for (int i = 0; i < 2; ++i) {
            int e = i * 256 + t;
            int o = e >> 4, k = e & 15;
            Bs[k * 34 + o] = W[(size_t)(o0 + o) * 2048 + c0 + k];
        }
        __syncthreads();
#pragma unroll
        for (int k = 0; k < 16; ++k) {
            float4 a = *(const float4*)&As[k][tm * 4];
            float2 b = *(const float2*)&Bs[k * 34 + to * 2];
            acc[0][0] += a.x * b.x; acc[0][1] += a.x * b.y;
            acc[1][0] += a.y * b.x; acc[1][1] += a.y * b.y;
            acc[2][0] += a.z * b.x; acc[2][1] += a.z * b.y;
            acc[3][0] += a.w * b.x; acc[3][1] += a.w * b.y;
        }
        __syncthreads();
    }

    // epilogue: bias+relu into Xs, then block-local 16x16 lnorm mix -> Y
#pragma unroll
    for (int i = 0; i < 4; ++i)
#pragma unroll
        for (int j = 0; j < 2; ++j)
            Xs[tm * 4 + i][to * 2 + j] = fmaxf(acc[i][j] + bias[o0 + to * 2 + j], 0.0f);
    __syncthreads();

    int nl = tm >> 2;                 // rows tm*4..tm*4+3 share one n
    int n = bm * 4 + nl;
    float yacc[4][2] = {};
#pragma unroll
    for (int r = 0; r < 4; ++r) {
        int i = (tm * 4 + r) & 15;
#pragma unroll
        for (int j = 0; j < 16; ++j) {
            float l = lns[nl * 272 + i * 17 + j];
            yacc[r][0] += l * Xs[nl * 16 + j][to * 2];
            yacc[r][1] += l * Xs[nl * 16 + j][to * 2 + 1];
        }
    }
#pragma unroll
    for (int r = 0; r < 4; ++r) {
        int i = (tm * 4 + r) & 15;
#pragma unroll
        for (int j = 0; j < 2; ++j)
            Y[(size_t)n * 4096 + i * 256 + o0 + to * 2 + j] = yacc[r][j];
    }
}

// ---------------------------------------------------------------------------
// K5: fc GEMM split-K, atomic accumulate onto bias-initialized out.
// M=128, N=512, K=4096 -> 8 K-chunks of 512. grid (4, 8, 8), block 256.
__global__ __launch_bounds__(256) void k_fc(const float* __restrict__ Y,
                                            const float* __restrict__ Fw,
                                            float* __restrict__ out) {
    int bn = blockIdx.x, bd = blockIdx.y, bk = blockIdx.z, t = threadIdx.x;
    int to = t & 15, tm = t >> 4;
    __shared__ float Ys[16 * 34];
    __shared__ float Fs[16 * 68];
    float acc[2][4] = {};
    int n0 = bn * 32, d0 = bd * 64, kbase = bk * 512;
    for (int c0 = kbase; c0 < kbase + 512; c0 += 16) {
#pragma unroll
        for (int i = 0; i < 2; ++i) {
            int e = i * 256 + t;
            int m = e >> 4, k = e & 15;
            Ys[k * 34 + m] = Y[(size_t)(n0 + m) * 4096 + c0 + k];
        }
#pragma unroll
        for (int i = 0; i < 4; ++i) {
            int e = i * 256 + t;
            int d = e >> 4, k = e & 15;
            Fs[k * 68 + d] = Fw[(size_t)(d0 + d) * 4096 + c0 + k];
        }
        __syncthreads();
#pragma unroll
        for (int k = 0; k < 16; ++k) {
            float2 a = *(const float2*)&Ys[k * 34 + tm * 2];
            float4 b = *(const float4*)&Fs[k * 68 + to * 4];
            acc[0][0] += a.x * b.x; acc[0][1] += a.x * b.y;
            acc[0][2] += a.x * b.z; acc[0][3] += a.x * b.w;
            acc[1][0] += a.y * b.x; acc[1][1] += a.y * b.y;
            acc[1][2] += a.y * b.z; acc[1][3] += a.y * b.w;
        }
        __syncthreads();
    }
#pragma unroll
    for (int i = 0; i < 2; ++i) {
        int nn = n0 + tm * 2 + i;
#pragma unroll
        for (int j = 0; j < 4; ++j) {
            int d = d0 + to * 4 + j;
            atomicAdd(&out[(size_t)nn * 512 + d], acc[i][j]);
        }
    }
}

// ---------------------------------------------------------------------------
extern "C" void kernel_launch(void* const* d_in, const int* in_sizes, int n_in,
                              void* d_out, int out_size, void* d_ws, size_t ws_size,
                              hipStream_t stream) {
    const float* snd    = (const float*)d_in[0];
    const float* conv_w = (const float*)d_in[1];
    const float* conv_b = (const float*)d_in[2];
    const float* fc_w   = (const float*)d_in[3];
    const float* fc_b   = (const float*)d_in[4];
    float* out = (float*)d_out;
    float* ws  = (float*)d_ws;

    float* partial = ws + WS_PARTIAL;
    int*   pos     = (int*)(ws + WS_POS);
    float* lnorm   = ws + WS_LNORM;
    float* nodesT  = ws + WS_NODEST;
    float* Y       = ws + WS_Y;

    k_init<<<256, 256, 0, stream>>>(out, fc_b);
    k_reduce<<<dim3(128, 8), 256, 0, stream>>>(snd, partial);
    k_topk_lnorm<<<128, 256, 0, stream>>>(partial, pos, lnorm);
    k_gather<<<dim3(128, 128), 256, 0, stream>>>(snd, pos, nodesT);
    k_conv<<<dim3(32, 8), 256, 0, stream>>>(nodesT, conv_w, conv_b, lnorm, Y);
    k_fc<<<dim3(4, 8, 8), 256, 0, stream>>>(Y, fc_w, out);
}

// Round 3
// 538.331 us; speedup vs baseline: 1.0795x; 1.0774x over previous
//
#include <hip/hip_runtime.h>
#include <math.h>

// Problem constants
#define NB   128
#define CIN  2048
#define PP   256
#define KK   16
#define CO   256
#define DO   512

// ws layout (float offsets)
#define WS_PARTIAL 0                         // [128][32][256] = 1,048,576
#define WS_POS     1048576                   // 2048 ints
#define WS_LNORM   1050624                   // 32768
#define WS_NODEST  1083392                   // [2048 c][2048 m] = 4,194,304
#define WS_XPART   5277696                   // 2 x [2048 m][256 o] = 1,048,576
#define WS_Y       6326272                   // [128][4096] = 524,288

// ---------------------------------------------------------------------------
// K0: init out with fc bias.
__global__ __launch_bounds__(256) void k_init(float* __restrict__ out,
                                              const float* __restrict__ fcb) {
    int i = blockIdx.x * 256 + threadIdx.x;
    out[i] = fcb[i & 511];
}

// ---------------------------------------------------------------------------
// K1: partial channel-sum. grid (128, 8), block 256. Streams all 256 MB once.
__global__ __launch_bounds__(256) void k_reduce(const float* __restrict__ snd,
                                                float* __restrict__ partial) {
    int n = blockIdx.x, chunk = blockIdx.y, t = threadIdx.x;
    int sub = t >> 6, p4 = t & 63;
    const float4* base = (const float4*)(snd + (size_t)n * CIN * PP
                                         + (size_t)(chunk * 256 + sub * 64) * PP) + p4;
    float4 acc = make_float4(0.f, 0.f, 0.f, 0.f);
#pragma unroll 4
    for (int c = 0; c < 64; ++c) {
        float4 v = base[c * 64];
        acc.x += v.x; acc.y += v.y; acc.z += v.z; acc.w += v.w;
    }
    ((float4*)(partial + (size_t)(n * 32 + chunk * 4 + sub) * 256))[p4] = acc;
}

// ---------------------------------------------------------------------------
// K2: finish reduction, top-16 (shuffle butterfly), remap, lnorm. grid 128.
__global__ __launch_bounds__(256) void k_topk_lnorm(const float* __restrict__ partial,
                                                    int* __restrict__ pos,
                                                    float* __restrict__ lnorm) {
    int n = blockIdx.x, t = threadIdx.x;
    int lane = t & 63, wv = t >> 6;
    __shared__ float wval[4];
    __shared__ int   widx[4];
    __shared__ int   sel[16];
    __shared__ float rr[16], cc[16], dinv[16];
    __shared__ float Ash[256];

    float v = 0.f;
#pragma unroll 8
    for (int j = 0; j < 32; ++j) v += partial[(size_t)(n * 32 + j) * 256 + t];

    for (int k = 0; k < 16; ++k) {
        float bv = v; int bi = t;
#pragma unroll
        for (int off = 32; off > 0; off >>= 1) {
            float ov = __shfl_xor(bv, off, 64);
            int   oi = __shfl_xor(bi, off, 64);
            if (ov > bv || (ov == bv && oi < bi)) { bv = ov; bi = oi; }
        }
        if (lane == 0) { wval[wv] = bv; widx[wv] = bi; }
        __syncthreads();
        float best = wval[0]; int besti = widx[0];
#pragma unroll
        for (int w = 1; w < 4; ++w) {
            float ww = wval[w]; int wi = widx[w];
            if (ww > best || (ww == best && wi < besti)) { best = ww; besti = wi; }
        }
        if (t == besti) v = -INFINITY;
        if (t == 0) sel[k] = besti;
        __syncthreads();
    }

    if (t < 16) {
        int idx = sel[t];
        int r = (idx < 16) ? (idx >> 4) : ((idx >> 4) - 1);
        int c = ((idx & 15) == 0) ? 15 : ((idx & 15) - 1);
        pos[n * 16 + t] = r * 16 + c;
        rr[t] = (float)r; cc[t] = (float)c;
    }
    __syncthreads();
    {
        int i = t >> 4, j = t & 15;
        float dr = rr[i] - rr[j], dc = cc[i] - cc[j];
        Ash[t] = expf(-(dr * dr + dc * dc) * (1.0f / 32.0f));
    }
    __syncthreads();
    if (t < 16) {
        float srow = 0.f;
#pragma unroll
        for (int j = 0; j < 16; ++j) srow += Ash[t * 16 + j];
        dinv[t] = rsqrtf(srow);
    }
    __syncthreads();
    {
        int i = t >> 4, j = t & 15;
        lnorm[(size_t)n * 256 + t] = Ash[t] * dinv[i] * dinv[j];
    }
}

// ---------------------------------------------------------------------------
// K3: DIRECT gather (no full-row re-stream). grid (128, 8), block 256.
// Reads only the ~10/16 cache lines per row actually containing picks;
// sounds is L3-resident after K1. Writes nodesT[c][m], m = n*16+k.
__global__ __launch_bounds__(256) void k_gather(const float* __restrict__ snd,
                                                const int* __restrict__ pos,
                                                float* __restrict__ nodesT) {
    int n = blockIdx.x, cb = blockIdx.y, t = threadIdx.x;
    __shared__ int lpos[16];
    if (t < 16) lpos[t] = pos[n * 16 + t];
    __syncthreads();
    int k = t & 15, cl = t >> 4;
    int p = lpos[k];
    const float* base = snd + (size_t)n * CIN * PP;
#pragma unroll
    for (int it = 0; it < 16; ++it) {
        int c = cb * 256 + it * 16 + cl;
        nodesT[(size_t)c * 2048 + n * 16 + k] = base[(size_t)c * PP + p];
    }
}

// ---------------------------------------------------------------------------
// K4: conv GEMM split-K. Xp[kc][m][o] = sum_{c in kc-half} nodesT[c][m]*W[o][c]
// Tile 64(m) x 64(o) x K1024, micro 4x4 (16 FMA / 32B LDS = VALU-peak-balanced).
// grid (32, 4, 2) = 256 blocks, block 256.
__global__ __launch_bounds__(256) void k_conv(const float* __restrict__ At,
                                              const float* __restrict__ W,
                                              float* __restrict__ Xpart) {
    int bm = blockIdx.x, bo = blockIdx.y, kc = blockIdx.z, t = threadIdx.x;
    int to = t & 15, tm = t >> 4;
    __shared__ float As[16][64];
    __shared__ float Bs[16 * 68];
    float acc[4][4] = {};
    int m0 = bm * 64, o0 = bo * 64;
    for (int c0 = kc * 1024; c0 < kc * 1024 + 1024; c0 += 16) {
#pragma unroll
        for (int i = 0; i < 4; ++i) {
            int e = i * 256 + t;
            int k = e >> 6, m = e & 63;
            As[k][m] = At[(size_t)(c0 + k) * 2048 + m0 + m];
        }
#pragma unroll
        for (int i = 0; i < 4; ++i) {
            int e = i * 256 + t;
            int o = e >> 4, k = e & 15;
            Bs[k * 68 + o] = W[(size_t)(o0 + o) * 2048 + c0 + k];
        }
        __syncthreads();
#pragma unroll
        for (int k = 0; k < 16; ++k) {
            float4 a = *(const float4*)&As[k][tm * 4];
            float4 b = *(const float4*)&Bs[k * 68 + to * 4];
            acc[0][0] += a.x * b.x; acc[0][1] += a.x * b.y; acc[0][2] += a.x * b.z; acc[0][3] += a.x * b.w;
            acc[1][0] += a.y * b.x; acc[1][1] += a.y * b.y; acc[1][2] += a.y * b.z; acc[1][3] += a.y * b.w;
            acc[2][0] += a.z * b.x; acc[2][1] += a.z * b.y; acc[2][2] += a.z * b.z; acc[2][3] += a.z * b.w;
            acc[3][0] += a.w * b.x; acc[3][1] += a.w * b.y; acc[3][2] += a.w * b.z; acc[3][3] += a.w * b.w;
        }
        __syncthreads();
    }
    float* Xp = Xpart + (size_t)kc * 524288;
#pragma unroll
    for (int i = 0; i < 4; ++i) {
        int m = m0 + tm * 4 + i;
        *(float4*)&Xp[(size_t)m * 256 + o0 + to * 4] =
            make_float4(acc[i][0], acc[i][1], acc[i][2], acc[i][3]);
    }
}

// ---------------------------------------------------------------------------
// K5: combine split-K partials + bias + relu + lnorm mix -> Y. grid 128.
__global__ __launch_bounds__(256) void k_xmix(const float* __restrict__ Xpart,
                                              const float* __restrict__ bias,
                                              const float* __restrict__ lnorm,
                                              float* __restrict__ Y) {
    int n = blockIdx.x, o = threadIdx.x;
    __shared__ float ln[256];
    ln[o] = lnorm[(size_t)n * 256 + o];
    float b = bias[o];
    __syncthreads();
    float xv[16];
#pragma unroll
    for (int j = 0; j < 16; ++j) {
        size_t off = (size_t)(n * 16 + j) * 256 + o;
        xv[j] = fmaxf(Xpart[off] + Xpart[524288 + off] + b, 0.0f);
    }
#pragma unroll
    for (int i = 0; i < 16; ++i) {
        float a = 0.f;
#pragma unroll
        for (int j = 0; j < 16; ++j) a += ln[i * 16 + j] * xv[j];
        Y[(size_t)n * 4096 + i * 256 + o] = a;
    }
}

// ---------------------------------------------------------------------------
// K6: fc GEMM split-K, atomic accumulate onto bias-initialized out.
// grid (4, 8, 8), block 256.
__global__ __launch_bounds__(256) void k_fc(const float* __restrict__ Y,
                                            const float* __restrict__ Fw,
                                            float* __restrict__ out) {
    int bn = blockIdx.x, bd = blockIdx.y, bk = blockIdx.z, t = threadIdx.x;
    int to = t & 15, tm = t >> 4;
    __shared__ float Ys[16 * 34];
    __shared__ float Fs[16 * 68];
    float acc[2][4] = {};
    int n0 = bn * 32, d0 = bd * 64, kbase = bk * 512;
    for (int c0 = kbase; c0 < kbase + 512; c0 += 16) {
#pragma unroll
        for (int i = 0; i < 2; ++i) {
            int e = i * 256 + t;
            int m = e >> 4, k = e & 15;
            Ys[k * 34 + m] = Y[(size_t)(n0 + m) * 4096 + c0 + k];
        }
#pragma unroll
        for (int i = 0; i < 4; ++i) {
            int e = i * 256 + t;
            int d = e >> 4, k = e & 15;
            Fs[k * 68 + d] = Fw[(size_t)(d0 + d) * 4096 + c0 + k];
        }
        __syncthreads();
#pragma unroll
        for (int k = 0; k < 16; ++k) {
            float2 a = *(const float2*)&Ys[k * 34 + tm * 2];
            float4 b = *(const float4*)&Fs[k * 68 + to * 4];
            acc[0][0] += a.x * b.x; acc[0][1] += a.x * b.y;
            acc[0][2] += a.x * b.z; acc[0][3] += a.x * b.w;
            acc[1][0] += a.y * b.x; acc[1][1] += a.y * b.y;
            acc[1][2] += a.y * b.z; acc[1][3] += a.y * b.w;
        }
        __syncthreads();
    }
#pragma unroll
    for (int i = 0; i < 2; ++i) {
        int nn = n0 + tm * 2 + i;
#pragma unroll
        for (int j = 0; j < 4; ++j) {
            int d = d0 + to * 4 + j;
            atomicAdd(&out[(size_t)nn * 512 + d], acc[i][j]);
        }
    }
}

// ---------------------------------------------------------------------------
extern "C" void kernel_launch(void* const* d_in, const int* in_sizes, int n_in,
                              void* d_out, int out_size, void* d_ws, size_t ws_size,
                              hipStream_t stream) {
    const float* snd    = (const float*)d_in[0];
    const float* conv_w = (const float*)d_in[1];
    const float* conv_b = (const float*)d_in[2];
    const float* fc_w   = (const float*)d_in[3];
    const float* fc_b   = (const float*)d_in[4];
    float* out = (float*)d_out;
    float* ws  = (float*)d_ws;

    float* partial = ws + WS_PARTIAL;
    int*   pos     = (int*)(ws + WS_POS);
    float* lnorm   = ws + WS_LNORM;
    float* nodesT  = ws + WS_NODEST;
    float* Xpart   = ws + WS_XPART;
    float* Y       = ws + WS_Y;

    k_init<<<256, 256, 0, stream>>>(out, fc_b);
    k_reduce<<<dim3(128, 8), 256, 0, stream>>>(snd, partial);
    k_topk_lnorm<<<128, 256, 0, stream>>>(partial, pos, lnorm);
    k_gather<<<dim3(128, 8), 256, 0, stream>>>(snd, pos, nodesT);
    k_conv<<<dim3(32, 4, 2), 256, 0, stream>>>(nodesT, conv_w, Xpart);
    k_xmix<<<128, 256, 0, stream>>>(Xpart, conv_b, lnorm, Y);
    k_fc<<<dim3(4, 8, 8), 256, 0, stream>>>(Y, fc_w, out);
}

// Round 4
// 487.513 us; speedup vs baseline: 1.1921x; 1.1042x over previous
//
#include <hip/hip_runtime.h>
#include <math.h>

typedef __attribute__((ext_vector_type(8))) short short8;
typedef __attribute__((ext_vector_type(4))) float f32x4;
typedef unsigned short ushort;
typedef unsigned int uint;

// Problem constants
#define NB   128
#define CIN  2048
#define PP   256
#define KK   16
#define CO   256
#define DO   512

// ws layout (float offsets)
#define WS_PARTIAL 0          // [128][32][256] = 1,048,576 floats
#define WS_POS     1048576    // 2048 ints
#define WS_LNORM   1050624    // 32768 floats
#define WS_NODES   1083392    // bf16 [2048 m][2048 c] = 8 MB = 2,097,152 slots
#define WS_WB      3180544    // bf16 [256 o][2048 c] = 1 MB = 262,144 slots
#define WS_XPART   3442688    // 2 x [2048 m][256 o] fp32 = 1,048,576
#define WS_Y       4491264    // [128][4096] fp32 = 524,288

__device__ __forceinline__ ushort f2bf(float f) {
    uint u = __builtin_bit_cast(uint, f);
    u += 0x7fffu + ((u >> 16) & 1u);   // RNE (inputs are normal floats)
    return (ushort)(u >> 16);
}

// ---------------------------------------------------------------------------
// K0: prep — convert conv_w to bf16 AND init out with fc bias. grid 768.
__global__ __launch_bounds__(256) void k_prep(const float* __restrict__ conv_w,
                                              ushort* __restrict__ Wb,
                                              const float* __restrict__ fcb,
                                              float* __restrict__ out) {
    int b = blockIdx.x, t = threadIdx.x;
    if (b < 512) {
        int idx = (b * 256 + t) * 4;
        float4 v = *(const float4*)(conv_w + idx);
        uint2 u;
        u.x = (uint)f2bf(v.x) | ((uint)f2bf(v.y) << 16);
        u.y = (uint)f2bf(v.z) | ((uint)f2bf(v.w) << 16);
        *(uint2*)(Wb + idx) = u;
    } else {
        int i = (b - 512) * 256 + t;
        out[i] = fcb[i & 511];
    }
}

// ---------------------------------------------------------------------------
// K1: partial channel-sum. grid (128, 8), block 256. Streams all 256 MB once.
__global__ __launch_bounds__(256) void k_reduce(const float* __restrict__ snd,
                                                float* __restrict__ partial) {
    int n = blockIdx.x, chunk = blockIdx.y, t = threadIdx.x;
    int sub = t >> 6, p4 = t & 63;
    const float4* base = (const float4*)(snd + (size_t)n * CIN * PP
                                         + (size_t)(chunk * 256 + sub * 64) * PP) + p4;
    float4 acc = make_float4(0.f, 0.f, 0.f, 0.f);
#pragma unroll 4
    for (int c = 0; c < 64; ++c) {
        float4 v = base[c * 64];
        acc.x += v.x; acc.y += v.y; acc.z += v.z; acc.w += v.w;
    }
    ((float4*)(partial + (size_t)(n * 32 + chunk * 4 + sub) * 256))[p4] = acc;
}

// ---------------------------------------------------------------------------
// K2: finish reduction, top-16 (shuffle butterfly), remap, lnorm. grid 128.
__global__ __launch_bounds__(256) void k_topk_lnorm(const float* __restrict__ partial,
                                                    int* __restrict__ pos,
                                                    float* __restrict__ lnorm) {
    int n = blockIdx.x, t = threadIdx.x;
    int lane = t & 63, wv = t >> 6;
    __shared__ float wval[4];
    __shared__ int   widx[4];
    __shared__ int   sel[16];
    __shared__ float rr[16], cc[16], dinv[16];
    __shared__ float Ash[256];

    float v = 0.f;
#pragma unroll 8
    for (int j = 0; j < 32; ++j) v += partial[(size_t)(n * 32 + j) * 256 + t];

    for (int k = 0; k < 16; ++k) {
        float bv = v; int bi = t;
#pragma unroll
        for (int off = 32; off > 0; off >>= 1) {
            float ov = __shfl_xor(bv, off, 64);
            int   oi = __shfl_xor(bi, off, 64);
            if (ov > bv || (ov == bv && oi < bi)) { bv = ov; bi = oi; }
        }
        if (lane == 0) { wval[wv] = bv; widx[wv] = bi; }
        __syncthreads();
        float best = wval[0]; int besti = widx[0];
#pragma unroll
        for (int w = 1; w < 4; ++w) {
            float ww = wval[w]; int wi = widx[w];
            if (ww > best || (ww == best && wi < besti)) { best = ww; besti = wi; }
        }
        if (t == besti) v = -INFINITY;
        if (t == 0) sel[k] = besti;
        __syncthreads();
    }

    if (t < 16) {
        int idx = sel[t];
        int r = (idx < 16) ? (idx >> 4) : ((idx >> 4) - 1);
        int c = ((idx & 15) == 0) ? 15 : ((idx & 15) - 1);
        pos[n * 16 + t] = r * 16 + c;
        rr[t] = (float)r; cc[t] = (float)c;
    }
    __syncthreads();
    {
        int i = t >> 4, j = t & 15;
        float dr = rr[i] - rr[j], dc = cc[i] - cc[j];
        Ash[t] = expf(-(dr * dr + dc * dc) * (1.0f / 32.0f));
    }
    __syncthreads();
    if (t < 16) {
        float srow = 0.f;
#pragma unroll
        for (int j = 0; j < 16; ++j) srow += Ash[t * 16 + j];
        dinv[t] = rsqrtf(srow);
    }
    __syncthreads();
    {
        int i = t >> 4, j = t & 15;
        lnorm[(size_t)n * 256 + t] = Ash[t] * dinv[i] * dinv[j];
    }
}

// ---------------------------------------------------------------------------
// K3: direct gather -> bf16 nodes[m][c], m = n*16+k (MFMA A-operand layout:
// k-contiguous rows). grid (128 n, 16 cb), block 256. Thread: k=t&15,
// ci=t>>4, handles c = cb*128 + ci*8 .. +7; one 16B store per thread.
__global__ __launch_bounds__(256) void k_gather(const float* __restrict__ snd,
                                                const int* __restrict__ pos,
                                                ushort* __restrict__ nodes) {
    int n = blockIdx.x, cb = blockIdx.y, t = threadIdx.x;
    __shared__ int lpos[16];
    if (t < 16) lpos[t] = pos[n * 16 + t];
    __syncthreads();
    int k = t & 15, ci = t >> 4;
    int p = lpos[k];
    const float* base = snd + (size_t)n * CIN * PP + (size_t)(cb * 128 + ci * 8) * PP + p;
    uint q[4];
#pragma unroll
    for (int i = 0; i < 4; ++i) {
        ushort a = f2bf(base[(size_t)(2 * i) * PP]);
        ushort b = f2bf(base[(size_t)(2 * i + 1) * PP]);
        q[i] = (uint)a | ((uint)b << 16);
    }
    uint4 qq = make_uint4(q[0], q[1], q[2], q[3]);
    *(uint4*)(nodes + (size_t)(n * 16 + k) * 2048 + cb * 128 + ci * 8) = qq;
}

// ---------------------------------------------------------------------------
// K4: conv GEMM via bf16 MFMA 16x16x32, split-K (kc=2).
// Block: 64m x 64o, BK=32; wave w = m-rows [w*16, w*16+16), 4 o-tiles each.
// LDS rows padded to 40 bf16 (80B) -> conflict-free ds_read_b128 fragments.
// grid (32, 4, 2) = 256 blocks.
__global__ __launch_bounds__(256) void k_conv(const ushort* __restrict__ nodes,
                                              const ushort* __restrict__ Wb,
                                              float* __restrict__ Xpart) {
    int bm = blockIdx.x, bo = blockIdx.y, kc = blockIdx.z, t = threadIdx.x;
    int w = t >> 6, l = t & 63;
    int lm = l & 15, quad = l >> 4;
    __shared__ ushort As[64 * 40];
    __shared__ ushort Bs[64 * 40];
    f32x4 acc[4] = {{0.f,0.f,0.f,0.f},{0.f,0.f,0.f,0.f},{0.f,0.f,0.f,0.f},{0.f,0.f,0.f,0.f}};
    int m0 = bm * 64, o0 = bo * 64;
    int row = t >> 2, seg = t & 3;
    const ushort* asrc = nodes + (size_t)(m0 + row) * 2048 + seg * 8;
    const ushort* bsrc = Wb + (size_t)(o0 + row) * 2048 + seg * 8;
    uint4* adst = (uint4*)(As + row * 40 + seg * 8);
    uint4* bdst = (uint4*)(Bs + row * 40 + seg * 8);
    const ushort* ard = As + (w * 16 + lm) * 40 + quad * 8;
    const ushort* brd = Bs + lm * 40 + quad * 8;

    for (int c0 = kc * 1024; c0 < kc * 1024 + 1024; c0 += 32) {
        *adst = *(const uint4*)(asrc + c0);
        *bdst = *(const uint4*)(bsrc + c0);
        __syncthreads();
        short8 af = *(const short8*)ard;
#pragma unroll
        for (int ot = 0; ot < 4; ++ot) {
            short8 bf = *(const short8*)(brd + ot * 16 * 40);
            acc[ot] = __builtin_amdgcn_mfma_f32_16x16x32_bf16(af, bf, acc[ot], 0, 0, 0);
        }
        __syncthreads();
    }

    float* Xp = Xpart + (size_t)kc * 524288;
#pragma unroll
    for (int ot = 0; ot < 4; ++ot) {
        int o = o0 + ot * 16 + lm;
#pragma unroll
        for (int r = 0; r < 4; ++r) {
            int m = m0 + w * 16 + quad * 4 + r;   // C/D: row = quad*4 + reg
            Xp[(size_t)m * 256 + o] = acc[ot][r];
        }
    }
}

// ---------------------------------------------------------------------------
// K5: combine split-K partials + bias + relu + lnorm mix -> Y (fp32). grid 128.
__global__ __launch_bounds__(256) void k_xmix(const float* __restrict__ Xpart,
                                              const float* __restrict__ bias,
                                              const float* __restrict__ lnorm,
                                              float* __restrict__ Y) {
    int n = blockIdx.x, o = threadIdx.x;
    __shared__ float ln[256];
    ln[o] = lnorm[(size_t)n * 256 + o];
    float b = bias[o];
    __syncthreads();
    float xv[16];
#pragma unroll
    for (int j = 0; j < 16; ++j) {
        size_t off = (size_t)(n * 16 + j) * 256 + o;
        xv[j] = fmaxf(Xpart[off] + Xpart[524288 + off] + b, 0.0f);
    }
#pragma unroll
    for (int i = 0; i < 16; ++i) {
        float a = 0.f;
#pragma unroll
        for (int j = 0; j < 16; ++j) a += ln[i * 16 + j] * xv[j];
        Y[(size_t)n * 4096 + i * 256 + o] = a;
    }
}

// ---------------------------------------------------------------------------
// K6: fc GEMM split-K fp32, atomic accumulate onto bias-initialized out.
// grid (4, 8, 8), block 256.
__global__ __launch_bounds__(256) void k_fc(const float* __restrict__ Y,
                                            const float* __restrict__ Fw,
                                            float* __restrict__ out) {
    int bn = blockIdx.x, bd = blockIdx.y, bk = blockIdx.z, t = threadIdx.x;
    int to = t & 15, tm = t >> 4;
    __shared__ float Ys[16 * 34];
    __shared__ float Fs[16 * 68];
    float acc[2][4] = {};
    int n0 = bn * 32, d0 = bd * 64, kbase = bk * 512;
    for (int c0 = kbase; c0 < kbase + 512; c0 += 16) {
#pragma unroll
        for (int i = 0; i < 2; ++i) {
            int e = i * 256 + t;
            int m = e >> 4, k = e & 15;
            Ys[k * 34 + m] = Y[(size_t)(n0 + m) * 4096 + c0 + k];
        }
#pragma unroll
        for (int i = 0; i < 4; ++i) {
            int e = i * 256 + t;
            int d = e >> 4, k = e & 15;
            Fs[k * 68 + d] = Fw[(size_t)(d0 + d) * 4096 + c0 + k];
        }
        __syncthreads();
#pragma unroll
        for (int k = 0; k < 16; ++k) {
            float2 a = *(const float2*)&Ys[k * 34 + tm * 2];
            float4 b = *(const float4*)&Fs[k * 68 + to * 4];
            acc[0][0] += a.x * b.x; acc[0][1] += a.x * b.y;
            acc[0][2] += a.x * b.z; acc[0][3] += a.x * b.w;
            acc[1][0] += a.y * b.x; acc[1][1] += a.y * b.y;
            acc[1][2] += a.y * b.z; acc[1][3] += a.y * b.w;
        }
        __syncthreads();
    }
#pragma unroll
    for (int i = 0; i < 2; ++i) {
        int nn = n0 + tm * 2 + i;
#pragma unroll
        for (int j = 0; j < 4; ++j) {
            int d = d0 + to * 4 + j;
            atomicAdd(&out[(size_t)nn * 512 + d], acc[i][j]);
        }
    }
}

// ---------------------------------------------------------------------------
extern "C" void kernel_launch(void* const* d_in, const int* in_sizes, int n_in,
                              void* d_out, int out_size, void* d_ws, size_t ws_size,
                              hipStream_t stream) {
    const float* snd    = (const float*)d_in[0];
    const float* conv_w = (const float*)d_in[1];
    const float* conv_b = (const float*)d_in[2];
    const float* fc_w   = (const float*)d_in[3];
    const float* fc_b   = (const float*)d_in[4];
    float* out = (float*)d_out;
    float* ws  = (float*)d_ws;

    float*  partial = ws + WS_PARTIAL;
    int*    pos     = (int*)(ws + WS_POS);
    float*  lnorm   = ws + WS_LNORM;
    ushort* nodes   = (ushort*)(ws + WS_NODES);
    ushort* Wb      = (ushort*)(ws + WS_WB);
    float*  Xpart   = ws + WS_XPART;
    float*  Y       = ws + WS_Y;

    k_prep<<<768, 256, 0, stream>>>(conv_w, Wb, fc_b, out);
    k_reduce<<<dim3(128, 8), 256, 0, stream>>>(snd, partial);
    k_topk_lnorm<<<128, 256, 0, stream>>>(partial, pos, lnorm);
    k_gather<<<dim3(128, 16), 256, 0, stream>>>(snd, pos, nodes);
    k_conv<<<dim3(32, 4, 2), 256, 0, stream>>>(nodes, Wb, Xpart);
    k_xmix<<<128, 256, 0, stream>>>(Xpart, conv_b, lnorm, Y);
    k_fc<<<dim3(4, 8, 8), 256, 0, stream>>>(Y, fc_w, out);
}